// Round 5
// baseline (496.851 us; speedup 1.0000x reference)
//
#include <hip/hip_runtime.h>
#include <math.h>

#define DD 64
static constexpr float GAMMA_C = 0.1f;
static constexpr float EPS_C = 0.1f;

// ---------------------------------------------------------------------------
// Prep: transposed weight copies (so later resident-weight loads coalesce).
//   aWT[k*64+j]   = W[j][k] - W[k][j] - GAMMA*(j==k)   (= aW^T)
//   phiWT[k*64+j] = phiW[j][k]
// ---------------------------------------------------------------------------
__global__ __launch_bounds__(256) void k_prep(const float* __restrict__ W1,
                                              const float* __restrict__ phiW1,
                                              const float* __restrict__ W2,
                                              const float* __restrict__ phiW2,
                                              float* __restrict__ aWT1,
                                              float* __restrict__ phiWT1,
                                              float* __restrict__ aWT2,
                                              float* __restrict__ phiWT2) {
  int idx = blockIdx.x * 256 + threadIdx.x;
  if (idx >= 4096) return;
  int k = idx >> 6, j = idx & 63;
  float g = (j == k) ? GAMMA_C : 0.f;
  aWT1[idx] = W1[j * 64 + k] - W1[k * 64 + j] - g;
  aWT2[idx] = W2[j * 64 + k] - W2[k * 64 + j] - g;
  phiWT1[idx] = phiW1[j * 64 + k];
  phiWT2[idx] = phiW2[j * 64 + k];
}

// ---------------------------------------------------------------------------
// CSR build: in-degree histogram -> exclusive scan -> fill (by destination).
// ---------------------------------------------------------------------------
__global__ __launch_bounds__(256) void k_hist(const int* __restrict__ col,
                                              int* __restrict__ hist, int e) {
  int i = blockIdx.x * blockDim.x + threadIdx.x;
  int stride = gridDim.x * blockDim.x;
  for (; i < e; i += stride) atomicAdd(&hist[col[i]], 1);
}

__global__ __launch_bounds__(256) void k_scan1(const int* __restrict__ hist,
                                               int* __restrict__ rs,
                                               int* __restrict__ bsum, int n) {
  __shared__ int wtot[4];
  int b = blockIdx.x, t = threadIdx.x;
  int base = b * 2048 + t * 8;
  int v[8];
  int s = 0;
#pragma unroll
  for (int u = 0; u < 8; ++u) {
    int idx = base + u;
    v[u] = (idx < n) ? hist[idx] : 0;
    s += v[u];
  }
  int lane = t & 63, wid = t >> 6;
  int ws = s;
#pragma unroll
  for (int d = 1; d < 64; d <<= 1) {
    int o = __shfl_up(ws, d);
    if (lane >= d) ws += o;
  }
  if (lane == 63) wtot[wid] = ws;
  __syncthreads();
  int off = 0;
  for (int w = 0; w < wid; ++w) off += wtot[w];
  int run = ws - s + off;  // exclusive start of this thread's chunk (in-block)
#pragma unroll
  for (int u = 0; u < 8; ++u) {
    int idx = base + u;
    if (idx < n) rs[idx] = run;
    run += v[u];
  }
  if (t == 255) bsum[b] = run;  // block total
}

__global__ void k_scan2(const int* __restrict__ bsum, int* __restrict__ boff,
                        int nb, int* __restrict__ rs, int n, int e) {
  int t = threadIdx.x;  // single wave; nb <= 64
  int v = (t < nb) ? bsum[t] : 0;
  int s = v;
#pragma unroll
  for (int d = 1; d < 64; d <<= 1) {
    int o = __shfl_up(s, d);
    if (t >= d) s += o;
  }
  if (t < nb) boff[t] = s - v;
  if (t == 0) rs[n] = e;
}

__global__ __launch_bounds__(256) void k_scan3_dinv(int* __restrict__ rs,
                                                    const int* __restrict__ boff,
                                                    const int* __restrict__ hist,
                                                    float* __restrict__ dinv, int n) {
  int i = blockIdx.x * blockDim.x + threadIdx.x;
  if (i < n) {
    rs[i] += boff[i >> 11];
    dinv[i] = rsqrtf((float)(hist[i] + 1));  // +1 self-loop
  }
}

// csr entry is just the source row (4B) — dinv[row] is folded into xw.
__global__ __launch_bounds__(256) void k_fill(const int* __restrict__ row,
                                              const int* __restrict__ col,
                                              const int* __restrict__ rs,
                                              int* __restrict__ fillc,
                                              int* __restrict__ csr, int e) {
  int i = blockIdx.x * blockDim.x + threadIdx.x;
  int stride = gridDim.x * blockDim.x;
  for (; i < e; i += stride) {
    int c = col[i];
    int r = row[i];
    int p = atomicAdd(&fillc[c], 1);
    csr[rs[c] + p] = r;
  }
}

// ---------------------------------------------------------------------------
// xw = dinv * (x @ phiW^T).  Wave-per-node, lane = output feature j.
// launch_bounds(256,4): VGPR cap 128 so phiWT stays register-resident.
// ---------------------------------------------------------------------------
__global__ __launch_bounds__(256, 4) void k_xw(const float* __restrict__ x,
                                               const float* __restrict__ phiWT,
                                               const float* __restrict__ dinv,
                                               float* __restrict__ xw, int n) {
  int lane = threadIdx.x & 63;
  int gw = __builtin_amdgcn_readfirstlane(
      (int)((blockIdx.x * blockDim.x + threadIdx.x) >> 6));
  int nw = (gridDim.x * blockDim.x) >> 6;
  float w[64];
#pragma unroll
  for (int k = 0; k < 64; ++k) w[k] = phiWT[k * 64 + lane];
  for (int i = gw; i < n; i += nw) {
    const float* xr = x + (size_t)i * DD;  // uniform address -> s_load
    float dv = dinv[i];                    // uniform
    float a0 = 0.f, a1 = 0.f, a2 = 0.f, a3 = 0.f;
#pragma unroll
    for (int k = 0; k < 64; k += 4) {
      a0 = fmaf(xr[k + 0], w[k + 0], a0);
      a1 = fmaf(xr[k + 1], w[k + 1], a1);
      a2 = fmaf(xr[k + 2], w[k + 2], a2);
      a3 = fmaf(xr[k + 3], w[k + 3], a3);
    }
    xw[(size_t)i * DD + lane] = dv * ((a0 + a1) + (a2 + a3));
  }
}

// ---------------------------------------------------------------------------
// Aggregation + antisym GEMV + combine. Wave per NODE-PAIR (i, i+1):
// their in-edges are contiguous in csr [rs[i], rs[i+2]) -> one 8-deep
// load pipeline over the joint range, uniform-predicated dual accumulate.
//   aggr_c = dinv[c] * ( xw[c] + sum_{r->c} xw[r] )      (xw pre-scaled)
//   val    = relu(xin + EPS*tanh((x@aW^T) + b + aggr))
// ---------------------------------------------------------------------------
template <bool FINAL>
__global__ __launch_bounds__(256, 4) void k_agg(const float* __restrict__ xin,
                                                const float* __restrict__ xw,
                                                const float* __restrict__ aWT,
                                                const float* __restrict__ b,
                                                const int* __restrict__ csr,
                                                const int* __restrict__ rs,
                                                const float* __restrict__ dinv,
                                                const float* __restrict__ outW,
                                                const float* __restrict__ outb,
                                                float* __restrict__ xo,
                                                float* __restrict__ out, int n) {
  int lane = threadIdx.x & 63;
  int gw = __builtin_amdgcn_readfirstlane(
      (int)((blockIdx.x * blockDim.x + threadIdx.x) >> 6));
  int nw = (gridDim.x * blockDim.x) >> 6;
  float w[64];
#pragma unroll
  for (int k = 0; k < 64; ++k) w[k] = aWT[k * 64 + lane];
  float bj = b[lane];
  float ow = FINAL ? outW[lane] : 0.f;
  for (int i = 2 * gw; i < n; i += 2 * nw) {
    bool hasB = (i + 1) < n;
    int s = rs[i];                        // uniform -> s_load
    int mid = rs[i + 1];
    int t = hasB ? rs[i + 2] : mid;
    size_t oA = (size_t)i * DD + lane;
    size_t oB = oA + DD;
    // self-loop terms (xw already carries dinv[src])
    float accA[4] = {xw[oA], 0.f, 0.f, 0.f};
    float accB[4] = {hasB ? xw[oB] : 0.f, 0.f, 0.f, 0.f};
    int k = s;
    for (; k + 7 < t; k += 8) {  // 8 gathers in flight
      int r[8];
#pragma unroll
      for (int u = 0; u < 8; ++u) r[u] = csr[k + u];  // uniform -> s_load
      float v[8];
#pragma unroll
      for (int u = 0; u < 8; ++u) v[u] = xw[(size_t)r[u] * DD + lane];
#pragma unroll
      for (int u = 0; u < 8; ++u) {
        float sA = (k + u < mid) ? 1.f : 0.f;  // uniform predicate
        accA[u & 3] = fmaf(v[u], sA, accA[u & 3]);
        accB[u & 3] = fmaf(v[u], 1.f - sA, accB[u & 3]);
      }
    }
    for (; k < t; ++k) {
      float v = xw[(size_t)csr[k] * DD + lane];
      float sA = (k < mid) ? 1.f : 0.f;
      accA[0] = fmaf(v, sA, accA[0]);
      accB[0] = fmaf(v, 1.f - sA, accB[0]);
    }
    // ---- node A epilogue ----
    {
      float aggr = dinv[i] * ((accA[0] + accA[1]) + (accA[2] + accA[3]));
      const float* xr = xin + (size_t)i * DD;  // uniform -> s_load
      float l0 = 0.f, l1 = 0.f, l2 = 0.f, l3 = 0.f;
#pragma unroll
      for (int kk = 0; kk < 64; kk += 4) {
        l0 = fmaf(xr[kk + 0], w[kk + 0], l0);
        l1 = fmaf(xr[kk + 1], w[kk + 1], l1);
        l2 = fmaf(xr[kk + 2], w[kk + 2], l2);
        l3 = fmaf(xr[kk + 3], w[kk + 3], l3);
      }
      float tot = ((l0 + l1) + (l2 + l3)) + bj + aggr;
      float val = fmaxf(fmaf(EPS_C, tanhf(tot), xin[oA]), 0.f);
      if (FINAL) {
        float p = val * ow;
#pragma unroll
        for (int sg = 32; sg > 0; sg >>= 1) p += __shfl_xor(p, sg);
        if (lane == 0) out[i] = p + outb[0];
      } else {
        xo[oA] = val;
      }
    }
    // ---- node B epilogue ----
    if (hasB) {
      float aggr = dinv[i + 1] * ((accB[0] + accB[1]) + (accB[2] + accB[3]));
      const float* xr = xin + (size_t)(i + 1) * DD;
      float l0 = 0.f, l1 = 0.f, l2 = 0.f, l3 = 0.f;
#pragma unroll
      for (int kk = 0; kk < 64; kk += 4) {
        l0 = fmaf(xr[kk + 0], w[kk + 0], l0);
        l1 = fmaf(xr[kk + 1], w[kk + 1], l1);
        l2 = fmaf(xr[kk + 2], w[kk + 2], l2);
        l3 = fmaf(xr[kk + 3], w[kk + 3], l3);
      }
      float tot = ((l0 + l1) + (l2 + l3)) + bj + aggr;
      float val = fmaxf(fmaf(EPS_C, tanhf(tot), xin[oB]), 0.f);
      if (FINAL) {
        float p = val * ow;
#pragma unroll
        for (int sg = 32; sg > 0; sg >>= 1) p += __shfl_xor(p, sg);
        if (lane == 0) out[i + 1] = p + outb[0];
      } else {
        xo[oB] = val;
      }
    }
  }
}

extern "C" void kernel_launch(void* const* d_in, const int* in_sizes, int n_in,
                              void* d_out, int out_size, void* d_ws, size_t ws_size,
                              hipStream_t stream) {
  const float* x     = (const float*)d_in[0];
  const float* W1    = (const float*)d_in[1];
  const float* phiW1 = (const float*)d_in[2];
  const float* b1    = (const float*)d_in[3];
  const float* W2    = (const float*)d_in[4];
  const float* phiW2 = (const float*)d_in[5];
  const float* b2    = (const float*)d_in[6];
  const float* outW  = (const float*)d_in[7];
  const float* outb  = (const float*)d_in[8];
  const int*   ei    = (const int*)d_in[9];

  int n = in_sizes[0] / DD;
  int e = in_sizes[9] / 2;
  const int* row = ei;
  const int* col = ei + e;
  float* out = (float*)d_out;

  // workspace carve (256B-aligned)
  char* w = (char*)d_ws;
  auto carve = [&](size_t bytes) {
    char* p = w;
    w += (bytes + 255) & ~(size_t)255;
    return p;
  };
  float* aWT1   = (float*)carve(4096 * 4);
  float* phiWT1 = (float*)carve(4096 * 4);
  float* aWT2   = (float*)carve(4096 * 4);
  float* phiWT2 = (float*)carve(4096 * 4);
  int*   hist   = (int*)carve((size_t)n * 4);   // hist+fillc adjacent:
  int*   fillc  = (int*)carve((size_t)n * 4);   //   one memset covers both
  int*   rs     = (int*)carve(((size_t)n + 1) * 4);
  int*   bsum   = (int*)carve(64 * 4);
  int*   boff   = (int*)carve(64 * 4);
  float* dinv   = (float*)carve((size_t)n * 4);
  int*   csr    = (int*)carve((size_t)e * 4);
  float* xw     = (float*)carve((size_t)n * DD * 4);
  float* x1     = (float*)carve((size_t)n * DD * 4);

  int nb_n   = (n + 255) / 256;
  int nb_e   = 2048;               // grid-stride blocks for edge kernels
  int nb_sc1 = (n + 2047) / 2048;  // scan blocks (49 for n=100k, <=64)
  int nb_xw  = 1024;               // 4096 waves, ~24 nodes each
  int nb_ag  = 2048;               // 8192 waves, ~6 node-pairs each

  size_t zbytes = (size_t)((char*)fillc - (char*)hist) + (size_t)n * 4;
  hipMemsetAsync(hist, 0, zbytes, stream);  // zeros hist and fillc

  // prep: transposed antisym/phi weights + CSR + dinv
  k_prep<<<16, 256, 0, stream>>>(W1, phiW1, W2, phiW2, aWT1, phiWT1, aWT2, phiWT2);
  k_hist<<<nb_e, 256, 0, stream>>>(col, hist, e);
  k_scan1<<<nb_sc1, 256, 0, stream>>>(hist, rs, bsum, n);
  k_scan2<<<1, 64, 0, stream>>>(bsum, boff, nb_sc1, rs, n, e);
  k_scan3_dinv<<<nb_n, 256, 0, stream>>>(rs, boff, hist, dinv, n);
  k_fill<<<nb_e, 256, 0, stream>>>(row, col, rs, fillc, csr, e);

  // layer 1
  k_xw<<<nb_xw, 256, 0, stream>>>(x, phiWT1, dinv, xw, n);
  k_agg<false><<<nb_ag, 256, 0, stream>>>(x, xw, aWT1, b1, csr, rs, dinv,
                                          nullptr, nullptr, x1, nullptr, n);

  // layer 2 (combine fused with output GEMV)
  k_xw<<<nb_xw, 256, 0, stream>>>(x1, phiWT2, dinv, xw, n);
  k_agg<true><<<nb_ag, 256, 0, stream>>>(x1, xw, aWT2, b2, csr, rs, dinv,
                                         outW, outb, nullptr, out, n);
}

// Round 6
// 492.720 us; speedup vs baseline: 1.0084x; 1.0084x over previous
//
#include <hip/hip_runtime.h>
#include <math.h>

#define DD 64
#define NSLICE 8     // dest-space slices; slice == blockIdx&7 -> one XCD each
#define NCHUNK 128   // edge-list chunks per slice pass
static constexpr float GAMMA_C = 0.1f;
static constexpr float EPS_C = 0.1f;

// ---------------------------------------------------------------------------
// Prep: transposed weight copies (so later resident-weight loads coalesce).
// ---------------------------------------------------------------------------
__global__ __launch_bounds__(256) void k_prep(const float* __restrict__ W1,
                                              const float* __restrict__ phiW1,
                                              const float* __restrict__ W2,
                                              const float* __restrict__ phiW2,
                                              float* __restrict__ aWT1,
                                              float* __restrict__ phiWT1,
                                              float* __restrict__ aWT2,
                                              float* __restrict__ phiWT2) {
  int idx = blockIdx.x * 256 + threadIdx.x;
  if (idx >= 4096) return;
  int k = idx >> 6, j = idx & 63;
  float g = (j == k) ? GAMMA_C : 0.f;
  aWT1[idx] = W1[j * 64 + k] - W1[k * 64 + j] - g;
  aWT2[idx] = W2[j * 64 + k] - W2[k * 64 + j] - g;
  phiWT1[idx] = phiW1[j * 64 + k];
  phiWT2[idx] = phiW2[j * 64 + k];
}

// ---------------------------------------------------------------------------
// Sliced in-degree histogram: block handles (slice, chunk); only counts
// edges whose dest is in its slice -> hist atomics stay XCD-local.
// ---------------------------------------------------------------------------
__global__ __launch_bounds__(256) void k_hist(const int* __restrict__ col,
                                              int* __restrict__ hist, int e, int n) {
  int slice = blockIdx.x & (NSLICE - 1);
  int chunk = blockIdx.x >> 3;
  int lo = (int)((long long)n * slice / NSLICE);
  int hi = (int)((long long)n * (slice + 1) / NSLICE);
  int per = (e + NCHUNK - 1) / NCHUNK;
  int s = chunk * per;
  int t = min(e, s + per);
  for (int i = s + threadIdx.x; i < t; i += 256) {
    int c = col[i];
    if (c >= lo && c < hi) atomicAdd(&hist[c], 1);
  }
}

__global__ __launch_bounds__(256) void k_scan1(const int* __restrict__ hist,
                                               int* __restrict__ rs,
                                               int* __restrict__ bsum, int n) {
  __shared__ int wtot[4];
  int b = blockIdx.x, t = threadIdx.x;
  int base = b * 2048 + t * 8;
  int v[8];
  int s = 0;
#pragma unroll
  for (int u = 0; u < 8; ++u) {
    int idx = base + u;
    v[u] = (idx < n) ? hist[idx] : 0;
    s += v[u];
  }
  int lane = t & 63, wid = t >> 6;
  int ws = s;
#pragma unroll
  for (int d = 1; d < 64; d <<= 1) {
    int o = __shfl_up(ws, d);
    if (lane >= d) ws += o;
  }
  if (lane == 63) wtot[wid] = ws;
  __syncthreads();
  int off = 0;
  for (int w = 0; w < wid; ++w) off += wtot[w];
  int run = ws - s + off;
#pragma unroll
  for (int u = 0; u < 8; ++u) {
    int idx = base + u;
    if (idx < n) rs[idx] = run;
    run += v[u];
  }
  if (t == 255) bsum[b] = run;
}

__global__ void k_scan2(const int* __restrict__ bsum, int* __restrict__ boff,
                        int nb, int* __restrict__ rs, int n, int e) {
  int t = threadIdx.x;  // single wave; nb <= 64
  int v = (t < nb) ? bsum[t] : 0;
  int s = v;
#pragma unroll
  for (int d = 1; d < 64; d <<= 1) {
    int o = __shfl_up(s, d);
    if (t >= d) s += o;
  }
  if (t < nb) boff[t] = s - v;
  if (t == 0) rs[n] = e;
}

__global__ __launch_bounds__(256) void k_scan3_dinv(int* __restrict__ rs,
                                                    const int* __restrict__ boff,
                                                    const int* __restrict__ hist,
                                                    float* __restrict__ dinv, int n) {
  int i = blockIdx.x * blockDim.x + threadIdx.x;
  if (i < n) {
    rs[i] += boff[i >> 11];
    dinv[i] = rsqrtf((float)(hist[i] + 1));  // +1 self-loop
  }
}

// ---------------------------------------------------------------------------
// Sliced CSR fill: block (slice, chunk) writes only csr entries for dests in
// its slice. All writers of a slice share one XCD (blockIdx&7) -> csr lines
// accumulate fully in that XCD's L2 (no cross-XCD partial-line writebacks).
// ---------------------------------------------------------------------------
__global__ __launch_bounds__(256) void k_fill(const int* __restrict__ row,
                                              const int* __restrict__ col,
                                              const int* __restrict__ rs,
                                              int* __restrict__ fillc,
                                              int* __restrict__ csr, int e, int n) {
  int slice = blockIdx.x & (NSLICE - 1);
  int chunk = blockIdx.x >> 3;
  int lo = (int)((long long)n * slice / NSLICE);
  int hi = (int)((long long)n * (slice + 1) / NSLICE);
  int per = (e + NCHUNK - 1) / NCHUNK;
  int s = chunk * per;
  int t = min(e, s + per);
  for (int i = s + threadIdx.x; i < t; i += 256) {
    int c = col[i];
    if (c >= lo && c < hi) {
      int p = atomicAdd(&fillc[c], 1);
      csr[rs[c] + p] = row[i];
    }
  }
}

// ---------------------------------------------------------------------------
// xw = bf16( dinv * (x @ phiW^T) ).  Wave-per-node, lane = output feature.
// ---------------------------------------------------------------------------
__global__ __launch_bounds__(256, 4) void k_xw(const float* __restrict__ x,
                                               const float* __restrict__ phiWT,
                                               const float* __restrict__ dinv,
                                               unsigned short* __restrict__ xwh,
                                               int n) {
  int lane = threadIdx.x & 63;
  int gw = __builtin_amdgcn_readfirstlane(
      (int)((blockIdx.x * blockDim.x + threadIdx.x) >> 6));
  int nw = (gridDim.x * blockDim.x) >> 6;
  float w[64];
#pragma unroll
  for (int k = 0; k < 64; ++k) w[k] = phiWT[k * 64 + lane];
  for (int i = gw; i < n; i += nw) {
    const float* xr = x + (size_t)i * DD;  // uniform address -> s_load
    float dv = dinv[i];                    // uniform
    float a0 = 0.f, a1 = 0.f, a2 = 0.f, a3 = 0.f;
#pragma unroll
    for (int k = 0; k < 64; k += 4) {
      a0 = fmaf(xr[k + 0], w[k + 0], a0);
      a1 = fmaf(xr[k + 1], w[k + 1], a1);
      a2 = fmaf(xr[k + 2], w[k + 2], a2);
      a3 = fmaf(xr[k + 3], w[k + 3], a3);
    }
    float r = dv * ((a0 + a1) + (a2 + a3));
    unsigned int u = __float_as_uint(r);
    unsigned int rb = (u + 0x7FFFu + ((u >> 16) & 1u)) >> 16;  // RNE to bf16
    xwh[(size_t)i * DD + lane] = (unsigned short)rb;
  }
}

// ---------------------------------------------------------------------------
// Aggregation + antisym GEMV + combine. Wave per node-pair; bf16 gathers
// (128B/row).  aggr_c = dinv[c]*(xw[c] + sum xw[r]); val = relu(x+EPS*tanh).
// ---------------------------------------------------------------------------
template <bool FINAL>
__global__ __launch_bounds__(256, 4) void k_agg(const float* __restrict__ xin,
                                                const unsigned short* __restrict__ xwh,
                                                const float* __restrict__ aWT,
                                                const float* __restrict__ b,
                                                const int* __restrict__ csr,
                                                const int* __restrict__ rs,
                                                const float* __restrict__ dinv,
                                                const float* __restrict__ outW,
                                                const float* __restrict__ outb,
                                                float* __restrict__ xo,
                                                float* __restrict__ out, int n) {
  int lane = threadIdx.x & 63;
  int gw = __builtin_amdgcn_readfirstlane(
      (int)((blockIdx.x * blockDim.x + threadIdx.x) >> 6));
  int nw = (gridDim.x * blockDim.x) >> 6;
  float w[64];
#pragma unroll
  for (int k = 0; k < 64; ++k) w[k] = aWT[k * 64 + lane];
  float bj = b[lane];
  float ow = FINAL ? outW[lane] : 0.f;
  for (int i = 2 * gw; i < n; i += 2 * nw) {
    bool hasB = (i + 1) < n;
    int s = rs[i];  // uniform -> s_load
    int mid = rs[i + 1];
    int t = hasB ? rs[i + 2] : mid;
    size_t oA = (size_t)i * DD + lane;
    size_t oB = oA + DD;
    float accA[4] = {__uint_as_float((unsigned int)xwh[oA] << 16), 0.f, 0.f, 0.f};
    float accB[4] = {hasB ? __uint_as_float((unsigned int)xwh[oB] << 16) : 0.f,
                     0.f, 0.f, 0.f};
    int k = s;
    for (; k + 7 < t; k += 8) {  // 8 gathers in flight
      int r[8];
#pragma unroll
      for (int u = 0; u < 8; ++u) r[u] = csr[k + u];  // uniform -> s_load
      float v[8];
#pragma unroll
      for (int u = 0; u < 8; ++u)
        v[u] = __uint_as_float((unsigned int)xwh[(size_t)r[u] * DD + lane] << 16);
#pragma unroll
      for (int u = 0; u < 8; ++u) {
        float sA = (k + u < mid) ? 1.f : 0.f;  // uniform predicate
        accA[u & 3] = fmaf(v[u], sA, accA[u & 3]);
        accB[u & 3] = fmaf(v[u], 1.f - sA, accB[u & 3]);
      }
    }
    for (; k < t; ++k) {
      float v = __uint_as_float((unsigned int)xwh[(size_t)csr[k] * DD + lane] << 16);
      float sA = (k < mid) ? 1.f : 0.f;
      accA[0] = fmaf(v, sA, accA[0]);
      accB[0] = fmaf(v, 1.f - sA, accB[0]);
    }
    // ---- node A epilogue ----
    {
      float aggr = dinv[i] * ((accA[0] + accA[1]) + (accA[2] + accA[3]));
      const float* xr = xin + (size_t)i * DD;  // uniform -> s_load
      float l0 = 0.f, l1 = 0.f, l2 = 0.f, l3 = 0.f;
#pragma unroll
      for (int kk = 0; kk < 64; kk += 4) {
        l0 = fmaf(xr[kk + 0], w[kk + 0], l0);
        l1 = fmaf(xr[kk + 1], w[kk + 1], l1);
        l2 = fmaf(xr[kk + 2], w[kk + 2], l2);
        l3 = fmaf(xr[kk + 3], w[kk + 3], l3);
      }
      float tot = ((l0 + l1) + (l2 + l3)) + bj + aggr;
      float val = fmaxf(fmaf(EPS_C, tanhf(tot), xin[oA]), 0.f);
      if (FINAL) {
        float p = val * ow;
#pragma unroll
        for (int sg = 32; sg > 0; sg >>= 1) p += __shfl_xor(p, sg);
        if (lane == 0) out[i] = p + outb[0];
      } else {
        xo[oA] = val;
      }
    }
    // ---- node B epilogue ----
    if (hasB) {
      float aggr = dinv[i + 1] * ((accB[0] + accB[1]) + (accB[2] + accB[3]));
      const float* xr = xin + (size_t)(i + 1) * DD;
      float l0 = 0.f, l1 = 0.f, l2 = 0.f, l3 = 0.f;
#pragma unroll
      for (int kk = 0; kk < 64; kk += 4) {
        l0 = fmaf(xr[kk + 0], w[kk + 0], l0);
        l1 = fmaf(xr[kk + 1], w[kk + 1], l1);
        l2 = fmaf(xr[kk + 2], w[kk + 2], l2);
        l3 = fmaf(xr[kk + 3], w[kk + 3], l3);
      }
      float tot = ((l0 + l1) + (l2 + l3)) + bj + aggr;
      float val = fmaxf(fmaf(EPS_C, tanhf(tot), xin[oB]), 0.f);
      if (FINAL) {
        float p = val * ow;
#pragma unroll
        for (int sg = 32; sg > 0; sg >>= 1) p += __shfl_xor(p, sg);
        if (lane == 0) out[i + 1] = p + outb[0];
      } else {
        xo[oB] = val;
      }
    }
  }
}

extern "C" void kernel_launch(void* const* d_in, const int* in_sizes, int n_in,
                              void* d_out, int out_size, void* d_ws, size_t ws_size,
                              hipStream_t stream) {
  const float* x     = (const float*)d_in[0];
  const float* W1    = (const float*)d_in[1];
  const float* phiW1 = (const float*)d_in[2];
  const float* b1    = (const float*)d_in[3];
  const float* W2    = (const float*)d_in[4];
  const float* phiW2 = (const float*)d_in[5];
  const float* b2    = (const float*)d_in[6];
  const float* outW  = (const float*)d_in[7];
  const float* outb  = (const float*)d_in[8];
  const int*   ei    = (const int*)d_in[9];

  int n = in_sizes[0] / DD;
  int e = in_sizes[9] / 2;
  const int* row = ei;
  const int* col = ei + e;
  float* out = (float*)d_out;

  // workspace carve (256B-aligned)
  char* w = (char*)d_ws;
  auto carve = [&](size_t bytes) {
    char* p = w;
    w += (bytes + 255) & ~(size_t)255;
    return p;
  };
  float* aWT1   = (float*)carve(4096 * 4);
  float* phiWT1 = (float*)carve(4096 * 4);
  float* aWT2   = (float*)carve(4096 * 4);
  float* phiWT2 = (float*)carve(4096 * 4);
  int*   hist   = (int*)carve((size_t)n * 4);   // hist+fillc adjacent:
  int*   fillc  = (int*)carve((size_t)n * 4);   //   one memset covers both
  int*   rs     = (int*)carve(((size_t)n + 1) * 4);
  int*   bsum   = (int*)carve(64 * 4);
  int*   boff   = (int*)carve(64 * 4);
  float* dinv   = (float*)carve((size_t)n * 4);
  int*   csr    = (int*)carve((size_t)e * 4);
  unsigned short* xwh = (unsigned short*)carve((size_t)n * DD * 2);
  float* x1     = (float*)carve((size_t)n * DD * 4);

  int nb_n   = (n + 255) / 256;
  int nb_sl  = NSLICE * NCHUNK;    // sliced edge kernels (1024 blocks)
  int nb_sc1 = (n + 2047) / 2048;  // scan blocks (49 for n=100k, <=64)
  int nb_xw  = 1024;               // 4096 waves
  int nb_ag  = 2048;               // 8192 waves, ~6 node-pairs each

  size_t zbytes = (size_t)((char*)fillc - (char*)hist) + (size_t)n * 4;
  hipMemsetAsync(hist, 0, zbytes, stream);  // zeros hist and fillc

  // prep: transposed antisym/phi weights + CSR + dinv
  k_prep<<<16, 256, 0, stream>>>(W1, phiW1, W2, phiW2, aWT1, phiWT1, aWT2, phiWT2);
  k_hist<<<nb_sl, 256, 0, stream>>>(col, hist, e, n);
  k_scan1<<<nb_sc1, 256, 0, stream>>>(hist, rs, bsum, n);
  k_scan2<<<1, 64, 0, stream>>>(bsum, boff, nb_sc1, rs, n, e);
  k_scan3_dinv<<<nb_n, 256, 0, stream>>>(rs, boff, hist, dinv, n);
  k_fill<<<nb_sl, 256, 0, stream>>>(row, col, rs, fillc, csr, e, n);

  // layer 1
  k_xw<<<nb_xw, 256, 0, stream>>>(x, phiWT1, dinv, xwh, n);
  k_agg<false><<<nb_ag, 256, 0, stream>>>(x, xwh, aWT1, b1, csr, rs, dinv,
                                          nullptr, nullptr, x1, nullptr, n);

  // layer 2 (combine fused with output GEMV)
  k_xw<<<nb_xw, 256, 0, stream>>>(x1, phiWT2, dinv, xwh, n);
  k_agg<true><<<nb_ag, 256, 0, stream>>>(x1, xwh, aWT2, b2, csr, rs, dinv,
                                         outW, outb, nullptr, out, n);
}

// Round 9
// 474.421 us; speedup vs baseline: 1.0473x; 1.0386x over previous
//
#include <hip/hip_runtime.h>
#include <math.h>

#define DD 64
#define NSLICE 8     // dest-space slices; slice == blockIdx&7 -> one XCD each
#define NCHUNK 128   // edge-list chunks per slice pass
static constexpr float GAMMA_C = 0.1f;
static constexpr float EPS_C = 0.1f;

__device__ __forceinline__ float bf16u(unsigned short h) {
  return __uint_as_float((unsigned int)h << 16);
}

// ---------------------------------------------------------------------------
// Prep: transposed weight copies.
//   aWT[k*64+j] = W[j][k] - W[k][j] - GAMMA*(j==k);  phiWT[k*64+j] = phiW[j][k]
// ---------------------------------------------------------------------------
__global__ __launch_bounds__(256) void k_prep(const float* __restrict__ W1,
                                              const float* __restrict__ phiW1,
                                              const float* __restrict__ W2,
                                              const float* __restrict__ phiW2,
                                              float* __restrict__ aWT1,
                                              float* __restrict__ phiWT1,
                                              float* __restrict__ aWT2,
                                              float* __restrict__ phiWT2) {
  int idx = blockIdx.x * 256 + threadIdx.x;
  if (idx >= 4096) return;
  int k = idx >> 6, j = idx & 63;
  float g = (j == k) ? GAMMA_C : 0.f;
  aWT1[idx] = W1[j * 64 + k] - W1[k * 64 + j] - g;
  aWT2[idx] = W2[j * 64 + k] - W2[k * 64 + j] - g;
  phiWT1[idx] = phiW1[j * 64 + k];
  phiWT2[idx] = phiW2[j * 64 + k];
}

// ---------------------------------------------------------------------------
// Sliced in-degree histogram (atomics stay XCD-local via blockIdx&7 slice).
// ---------------------------------------------------------------------------
__global__ __launch_bounds__(256) void k_hist(const int* __restrict__ col,
                                              int* __restrict__ hist, int e, int n) {
  int slice = blockIdx.x & (NSLICE - 1);
  int chunk = blockIdx.x >> 3;
  int lo = (int)((long long)n * slice / NSLICE);
  int hi = (int)((long long)n * (slice + 1) / NSLICE);
  int per = (e + NCHUNK - 1) / NCHUNK;
  int s = chunk * per;
  int t = min(e, s + per);
  for (int i = s + threadIdx.x; i < t; i += 256) {
    int c = col[i];
    if (c >= lo && c < hi) atomicAdd(&hist[c], 1);
  }
}

__global__ __launch_bounds__(256) void k_scan1(const int* __restrict__ hist,
                                               int* __restrict__ rs,
                                               int* __restrict__ bsum, int n) {
  __shared__ int wtot[4];
  int b = blockIdx.x, t = threadIdx.x;
  int base = b * 2048 + t * 8;
  int v[8];
  int s = 0;
#pragma unroll
  for (int u = 0; u < 8; ++u) {
    int idx = base + u;
    v[u] = (idx < n) ? hist[idx] : 0;
    s += v[u];
  }
  int lane = t & 63, wid = t >> 6;
  int ws = s;
#pragma unroll
  for (int d = 1; d < 64; d <<= 1) {
    int o = __shfl_up(ws, d);
    if (lane >= d) ws += o;
  }
  if (lane == 63) wtot[wid] = ws;
  __syncthreads();
  int off = 0;
  for (int w = 0; w < wid; ++w) off += wtot[w];
  int run = ws - s + off;
#pragma unroll
  for (int u = 0; u < 8; ++u) {
    int idx = base + u;
    if (idx < n) rs[idx] = run;
    run += v[u];
  }
  if (t == 255) bsum[b] = run;
}

__global__ void k_scan2(const int* __restrict__ bsum, int* __restrict__ boff,
                        int nb, int* __restrict__ rs, int n, int e) {
  int t = threadIdx.x;  // single wave; nb <= 64
  int v = (t < nb) ? bsum[t] : 0;
  int s = v;
#pragma unroll
  for (int d = 1; d < 64; d <<= 1) {
    int o = __shfl_up(s, d);
    if (t >= d) s += o;
  }
  if (t < nb) boff[t] = s - v;
  if (t == 0) rs[n] = e;
}

__global__ __launch_bounds__(256) void k_scan3_dinv(int* __restrict__ rs,
                                                    const int* __restrict__ boff,
                                                    const int* __restrict__ hist,
                                                    float* __restrict__ dinv, int n) {
  int i = blockIdx.x * blockDim.x + threadIdx.x;
  if (i < n) {
    rs[i] += boff[i >> 11];
    dinv[i] = rsqrtf((float)(hist[i] + 1));  // +1 self-loop
  }
}

// ---------------------------------------------------------------------------
// Sliced CSR fill (writers of a slice share one XCD -> full-line writebacks).
// ---------------------------------------------------------------------------
__global__ __launch_bounds__(256) void k_fill(const int* __restrict__ row,
                                              const int* __restrict__ col,
                                              const int* __restrict__ rs,
                                              int* __restrict__ fillc,
                                              int* __restrict__ csr, int e, int n) {
  int slice = blockIdx.x & (NSLICE - 1);
  int chunk = blockIdx.x >> 3;
  int lo = (int)((long long)n * slice / NSLICE);
  int hi = (int)((long long)n * (slice + 1) / NSLICE);
  int per = (e + NCHUNK - 1) / NCHUNK;
  int s = chunk * per;
  int t = min(e, s + per);
  for (int i = s + threadIdx.x; i < t; i += 256) {
    int c = col[i];
    if (c >= lo && c < hi) {
      int p = atomicAdd(&fillc[c], 1);
      csr[rs[c] + p] = row[i];
    }
  }
}

// ---------------------------------------------------------------------------
// xw = bf16( dinv * (x @ phiW^T) ).  Wave-per-QUAD of nodes, lane = out feat.
// Weights in LDS, read blocked (8 at a time) and reused across 4 nodes ->
// VMEM pipe carries only x-row s_loads + row stores.
// ---------------------------------------------------------------------------
__global__ __launch_bounds__(256, 4) void k_xw(const float* __restrict__ x,
                                               const float* __restrict__ phiWT,
                                               const float* __restrict__ dinv,
                                               unsigned short* __restrict__ xwh,
                                               int n) {
  __shared__ float lw[4096];
  for (int u = threadIdx.x; u < 4096; u += 256) lw[u] = phiWT[u];
  __syncthreads();
  int lane = threadIdx.x & 63;
  int gw = __builtin_amdgcn_readfirstlane(
      (int)((blockIdx.x * blockDim.x + threadIdx.x) >> 6));
  int nw = (gridDim.x * blockDim.x) >> 6;
  for (int i = 4 * gw; i < n; i += 4 * nw) {
    int j1 = min(i + 1, n - 1), j2 = min(i + 2, n - 1), j3 = min(i + 3, n - 1);
    const float* xr0 = x + (size_t)i * DD;   // uniform -> s_load
    const float* xr1 = x + (size_t)j1 * DD;
    const float* xr2 = x + (size_t)j2 * DD;
    const float* xr3 = x + (size_t)j3 * DD;
    float l0 = 0.f, l1 = 0.f, l2 = 0.f, l3 = 0.f;
#pragma unroll
    for (int blk = 0; blk < 8; ++blk) {
      float w8[8];
#pragma unroll
      for (int u = 0; u < 8; ++u) w8[u] = lw[(blk * 8 + u) * 64 + lane];
#pragma unroll
      for (int u = 0; u < 8; ++u) {
        int kk = blk * 8 + u;
        l0 = fmaf(xr0[kk], w8[u], l0);
        l1 = fmaf(xr1[kk], w8[u], l1);
        l2 = fmaf(xr2[kk], w8[u], l2);
        l3 = fmaf(xr3[kk], w8[u], l3);
      }
    }
    float r0 = dinv[i] * l0, r1 = dinv[j1] * l1;
    float r2 = dinv[j2] * l2, r3 = dinv[j3] * l3;
    auto pack = [](float r) {
      unsigned int u = __float_as_uint(r);
      return (unsigned short)((u + 0x7FFFu + ((u >> 16) & 1u)) >> 16);  // RNE
    };
    size_t o = (size_t)i * DD + lane;
    xwh[o] = pack(r0);
    if (i + 1 < n) xwh[o + DD] = pack(r1);
    if (i + 2 < n) xwh[o + 2 * DD] = pack(r2);
    if (i + 3 < n) xwh[o + 3 * DD] = pack(r3);
  }
}

// ---------------------------------------------------------------------------
// Aggregation + antisym GEMV + combine. Wave per QUAD; joint CSR range
// [rs[i], rs[i+4]) with suffix-sum predicated accumulation (uniform scalar
// predicates); double-buffered 8-deep gather pipeline; weights in LDS.
// ---------------------------------------------------------------------------
template <bool FINAL>
__global__ __launch_bounds__(256, 4) void k_agg(const float* __restrict__ xin,
                                                const unsigned short* __restrict__ xwh,
                                                const float* __restrict__ aWT,
                                                const float* __restrict__ b,
                                                const int* __restrict__ csr,
                                                const int* __restrict__ rs,
                                                const float* __restrict__ dinv,
                                                const float* __restrict__ outW,
                                                const float* __restrict__ outb,
                                                float* __restrict__ xo,
                                                float* __restrict__ out, int n) {
  __shared__ float lw[4096];
  for (int u = threadIdx.x; u < 4096; u += 256) lw[u] = aWT[u];
  __syncthreads();
  int lane = threadIdx.x & 63;
  int gw = __builtin_amdgcn_readfirstlane(
      (int)((blockIdx.x * blockDim.x + threadIdx.x) >> 6));
  int nw = (gridDim.x * blockDim.x) >> 6;
  float bj = b[lane];
  float ow = FINAL ? outW[lane] : 0.f;
  for (int i = 4 * gw; i < n; i += 4 * nw) {
    int i1 = min(i + 1, n), i2 = min(i + 2, n), i3 = min(i + 3, n), i4 = min(i + 4, n);
    int e0 = rs[i], m1 = rs[i1], m2 = rs[i2], m3 = rs[i3], e4 = rs[i4];
    float t0 = 0.f, t1 = 0.f, t2 = 0.f, t3 = 0.f;
    if (e0 < e4) {
      int e4m1 = e4 - 1;
      int rA[8], rB[8];
      float vA[8], vB[8];
      auto loadB = [&](int kb, int* rX, float* vX) {
#pragma unroll
        for (int u = 0; u < 8; ++u) rX[u] = csr[min(kb + u, e4m1)];  // uniform
#pragma unroll
        for (int u = 0; u < 8; ++u)
          vX[u] = bf16u(xwh[(size_t)rX[u] * DD + lane]);
      };
      auto consB = [&](int kb, const float* vX) {
#pragma unroll
        for (int u = 0; u < 8; ++u) {
          int ke = kb + u;  // uniform
          float vv = (ke < e4) ? vX[u] : 0.f;
          t0 += vv;
          t1 = fmaf((ke >= m1) ? 1.f : 0.f, vv, t1);
          t2 = fmaf((ke >= m2) ? 1.f : 0.f, vv, t2);
          t3 = fmaf((ke >= m3) ? 1.f : 0.f, vv, t3);
        }
      };
      int k = e0;
      loadB(k, rA, vA);
      while (true) {
        int kn = k + 8;
        if (kn < e4) {
          loadB(kn, rB, vB);  // next batch in flight while consuming A
          consB(k, vA);
        } else {
          consB(k, vA);
          break;
        }
        k = kn;
        kn = k + 8;
        if (kn < e4) {
          loadB(kn, rA, vA);
          consB(k, vB);
        } else {
          consB(k, vB);
          break;
        }
        k = kn;
      }
    }
    // self-loop terms (xwh rows already dinv-scaled) and suffix differences
    size_t o0 = (size_t)i * DD + lane;
    float s0 = bf16u(xwh[o0]);
    float s1 = (i + 1 < n) ? bf16u(xwh[o0 + DD]) : 0.f;
    float s2 = (i + 2 < n) ? bf16u(xwh[o0 + 2 * DD]) : 0.f;
    float s3 = (i + 3 < n) ? bf16u(xwh[o0 + 3 * DD]) : 0.f;
    float g0 = dinv[i] * ((t0 - t1) + s0);
    float g1 = (i + 1 < n) ? dinv[i1] * ((t1 - t2) + s1) : 0.f;
    float g2 = (i + 2 < n) ? dinv[i2] * ((t2 - t3) + s2) : 0.f;
    float g3 = (i + 3 < n) ? dinv[i3] * (t3 + s3) : 0.f;
    // blocked antisym GEMV from LDS (8 w's reused across 4 nodes)
    int j1 = min(i + 1, n - 1), j2 = min(i + 2, n - 1), j3 = min(i + 3, n - 1);
    const float* xr0 = xin + (size_t)i * DD;  // uniform -> s_load
    const float* xr1 = xin + (size_t)j1 * DD;
    const float* xr2 = xin + (size_t)j2 * DD;
    const float* xr3 = xin + (size_t)j3 * DD;
    float l0 = 0.f, l1 = 0.f, l2 = 0.f, l3 = 0.f;
#pragma unroll
    for (int blk = 0; blk < 8; ++blk) {
      float w8[8];
#pragma unroll
      for (int u = 0; u < 8; ++u) w8[u] = lw[(blk * 8 + u) * 64 + lane];
#pragma unroll
      for (int u = 0; u < 8; ++u) {
        int kk = blk * 8 + u;
        l0 = fmaf(xr0[kk], w8[u], l0);
        l1 = fmaf(xr1[kk], w8[u], l1);
        l2 = fmaf(xr2[kk], w8[u], l2);
        l3 = fmaf(xr3[kk], w8[u], l3);
      }
    }
    float val0 = fmaxf(fmaf(EPS_C, tanhf(l0 + bj + g0), xin[o0]), 0.f);
    float val1 = fmaxf(fmaf(EPS_C, tanhf(l1 + bj + g1), xin[(size_t)j1 * DD + lane]), 0.f);
    float val2 = fmaxf(fmaf(EPS_C, tanhf(l2 + bj + g2), xin[(size_t)j2 * DD + lane]), 0.f);
    float val3 = fmaxf(fmaf(EPS_C, tanhf(l3 + bj + g3), xin[(size_t)j3 * DD + lane]), 0.f);
    if (FINAL) {
      float p0 = val0 * ow, p1 = val1 * ow, p2 = val2 * ow, p3 = val3 * ow;
#pragma unroll
      for (int sg = 32; sg > 0; sg >>= 1) {
        p0 += __shfl_xor(p0, sg);
        p1 += __shfl_xor(p1, sg);
        p2 += __shfl_xor(p2, sg);
        p3 += __shfl_xor(p3, sg);
      }
      if (lane == 0) {
        float ob = outb[0];
        out[i] = p0 + ob;
        if (i + 1 < n) out[i + 1] = p1 + ob;
        if (i + 2 < n) out[i + 2] = p2 + ob;
        if (i + 3 < n) out[i + 3] = p3 + ob;
      }
    } else {
      xo[o0] = val0;
      if (i + 1 < n) xo[o0 + DD] = val1;
      if (i + 2 < n) xo[o0 + 2 * DD] = val2;
      if (i + 3 < n) xo[o0 + 3 * DD] = val3;
    }
  }
}

extern "C" void kernel_launch(void* const* d_in, const int* in_sizes, int n_in,
                              void* d_out, int out_size, void* d_ws, size_t ws_size,
                              hipStream_t stream) {
  const float* x     = (const float*)d_in[0];
  const float* W1    = (const float*)d_in[1];
  const float* phiW1 = (const float*)d_in[2];
  const float* b1    = (const float*)d_in[3];
  const float* W2    = (const float*)d_in[4];
  const float* phiW2 = (const float*)d_in[5];
  const float* b2    = (const float*)d_in[6];
  const float* outW  = (const float*)d_in[7];
  const float* outb  = (const float*)d_in[8];
  const int*   ei    = (const int*)d_in[9];

  int n = in_sizes[0] / DD;
  int e = in_sizes[9] / 2;
  const int* row = ei;
  const int* col = ei + e;
  float* out = (float*)d_out;

  // workspace carve (256B-aligned)
  char* w = (char*)d_ws;
  auto carve = [&](size_t bytes) {
    char* p = w;
    w += (bytes + 255) & ~(size_t)255;
    return p;
  };
  float* aWT1   = (float*)carve(4096 * 4);
  float* phiWT1 = (float*)carve(4096 * 4);
  float* aWT2   = (float*)carve(4096 * 4);
  float* phiWT2 = (float*)carve(4096 * 4);
  int*   hist   = (int*)carve((size_t)n * 4);   // hist+fillc adjacent:
  int*   fillc  = (int*)carve((size_t)n * 4);   //   one memset covers both
  int*   rs     = (int*)carve(((size_t)n + 1) * 4);
  int*   bsum   = (int*)carve(64 * 4);
  int*   boff   = (int*)carve(64 * 4);
  float* dinv   = (float*)carve((size_t)n * 4);
  int*   csr    = (int*)carve((size_t)e * 4);
  unsigned short* xwh = (unsigned short*)carve((size_t)n * DD * 2);
  float* x1     = (float*)carve((size_t)n * DD * 4);

  int nb_n   = (n + 255) / 256;
  int nb_sl  = NSLICE * NCHUNK;    // sliced edge kernels (1024 blocks)
  int nb_sc1 = (n + 2047) / 2048;  // scan blocks (49 for n=100k, <=64)
  int nb_xw  = 1024;               // 4096 waves x 4 nodes
  int nb_ag  = 2048;               // 8192 waves x 4 nodes

  size_t zbytes = (size_t)((char*)fillc - (char*)hist) + (size_t)n * 4;
  hipMemsetAsync(hist, 0, zbytes, stream);  // zeros hist and fillc

  // prep: transposed antisym/phi weights + CSR + dinv
  k_prep<<<16, 256, 0, stream>>>(W1, phiW1, W2, phiW2, aWT1, phiWT1, aWT2, phiWT2);
  k_hist<<<nb_sl, 256, 0, stream>>>(col, hist, e, n);
  k_scan1<<<nb_sc1, 256, 0, stream>>>(hist, rs, bsum, n);
  k_scan2<<<1, 64, 0, stream>>>(bsum, boff, nb_sc1, rs, n, e);
  k_scan3_dinv<<<nb_n, 256, 0, stream>>>(rs, boff, hist, dinv, n);
  k_fill<<<nb_sl, 256, 0, stream>>>(row, col, rs, fillc, csr, e, n);

  // layer 1
  k_xw<<<nb_xw, 256, 0, stream>>>(x, phiWT1, dinv, xwh, n);
  k_agg<false><<<nb_ag, 256, 0, stream>>>(x, xwh, aWT1, b1, csr, rs, dinv,
                                          nullptr, nullptr, x1, nullptr, n);

  // layer 2 (combine fused with output GEMV)
  k_xw<<<nb_xw, 256, 0, stream>>>(x1, phiWT2, dinv, xwh, n);
  k_agg<true><<<nb_ag, 256, 0, stream>>>(x1, xwh, aWT2, b2, csr, rs, dinv,
                                         outW, outb, nullptr, out, n);
}